// Round 2
// baseline (2282.724 us; speedup 1.0000x reference)
//
#include <hip/hip_runtime.h>

// LocalFeatureAggregation — round 1: correct fp32 kernel (inputs/outputs are fp32).
// B=2, N=65536, K=16, Cr=10, Cin=64, Cnb=64, Ccat=128, Cout=128.

#define BATCH  2
#define NPOINT 65536
#define KNB    16
#define CR     10
#define CIN    64
#define CNB    64
#define CCAT   128
#define COUT   128
#define NPTS   (BATCH * NPOINT)      // 131072

#define NBLK   256                   // 1 block per CU (persistent-style; correct regardless)
#define NGRP   4                     // point-groups per block (128 thr each)
#define TPB    (NGRP * 128)          // 512 threads
#define PITCH  20                    // feaT row pitch (floats): 80 B, 16 B-aligned rows
#define ITERS  (NPTS / (NBLK * NGRP))// 128, exact — no tail, uniform barriers

typedef const float* fp;

__global__ __launch_bounds__(TPB) void lfa_kernel(
    fp feature, fp raw, const int* __restrict__ nidx,
    fp W_nb, fp b_nb, fp g_nb, fp be_nb, fp m_nb, fp v_nb,
    fp W_attn,
    fp W_out, fp b_out, fp g_out, fp be_out, fp m_out, fp v_out,
    fp W_sc, fp b_sc, fp g_sc, fp be_sc, fp m_sc, fp v_sc,
    float* __restrict__ out)
{
    __shared__ float Wattn_s[CCAT * CCAT];          // 64 KB
    __shared__ float feaT[NGRP][CCAT][PITCH];       // 40 KB  fea^T: [channel][k]
    __shared__ float Wnb_s[CR][CNB];                // 2.5 KB
    __shared__ float rawL[NGRP][KNB * CR];          // 2.5 KB
    __shared__ int   idxL[NGRP][KNB];
    __shared__ float featL[NGRP][CIN];              // center-point feature
    __shared__ float pooledL[NGRP][CCAT];

    const int tid = threadIdx.x;
    const int g   = tid >> 7;        // group 0..3
    const int d   = tid & 127;       // channel 0..127 within group

    // ---- one-time staging: W_attn, W_nb into LDS ----
    for (int i = tid; i < CCAT * CCAT; i += TPB)
        Wattn_s[i] = W_attn[i];
    for (int i = tid; i < CR * CNB; i += TPB)
        (&Wnb_s[0][0])[i] = W_nb[i];

    // ---- fold BN constants into per-thread scale/bias registers ----
    float s_nb = 0.f, bi_nb = 0.f;
    if (d < CNB) {
        s_nb  = g_nb[d] * rsqrtf(v_nb[d] + 1e-5f);
        bi_nb = (b_nb[d] - m_nb[d]) * s_nb + be_nb[d];
    }
    const float s_o = g_out[d] * rsqrtf(v_out[d] + 1e-5f);
    const float s_s = g_sc[d]  * rsqrtf(v_sc[d]  + 1e-5f);
    const float bias3 =
          (b_out[d] - m_out[d]) * s_o + be_out[d]
        + (b_sc[d]  - m_sc[d])  * s_s + be_sc[d];

    __syncthreads();

    for (int it = 0; it < ITERS; ++it) {
        const int p = it * (NBLK * NGRP) + blockIdx.x * NGRP + g;  // point id
        const int b = p >> 16;                                     // batch (N=65536)

        // ---- stage idx / raw / center feature ----
        if (d < KNB) idxL[g][d] = nidx[p * KNB + d];
        if (d >= 64) featL[g][d - 64] = feature[(size_t)p * CIN + (d - 64)];
        for (int i = d; i < KNB * CR; i += 128)
            rawL[g][i] = raw[(size_t)p * (KNB * CR) + i];
        __syncthreads();

        // ---- phase 1: build fea^T[128][16] in LDS ----
        if (d < 64) {
            // wave 0 of the group: neighbor-MLP channel d
            float nbv[KNB];
            #pragma unroll
            for (int k = 0; k < KNB; ++k) {
                float acc = 0.f;
                #pragma unroll
                for (int c = 0; c < CR; ++c)
                    acc += rawL[g][k * CR + c] * Wnb_s[c][d];
                float x = acc * s_nb + bi_nb;
                nbv[k] = x >= 0.f ? x : 0.2f * x;
            }
            #pragma unroll
            for (int k0 = 0; k0 < KNB; k0 += 4)
                *(float4*)&feaT[g][64 + d][k0] =
                    make_float4(nbv[k0], nbv[k0+1], nbv[k0+2], nbv[k0+3]);
        } else {
            // wave 1 of the group: gather channel c of the 16 neighbors (coalesced per k)
            const int c = d - 64;
            float gvv[KNB];
            #pragma unroll
            for (int k = 0; k < KNB; ++k) {
                const int ni = idxL[g][k];
                gvv[k] = feature[(size_t)((b << 16) + ni) * CIN + c];
            }
            #pragma unroll
            for (int k0 = 0; k0 < KNB; k0 += 4)
                *(float4*)&feaT[g][c][k0] =
                    make_float4(gvv[k0], gvv[k0+1], gvv[k0+2], gvv[k0+3]);
        }
        __syncthreads();

        // ---- phase 2: attn logits A[k] = sum_c fea[k][c] * W_attn[c][d] ----
        float A[KNB];
        #pragma unroll
        for (int k = 0; k < KNB; ++k) A[k] = 0.f;

        #pragma unroll 4
        for (int c = 0; c < CCAT; ++c) {
            const float w = Wattn_s[c * CCAT + d];
            const float4* frr = (const float4*)&feaT[g][c][0];
            const float4 f0 = frr[0], f1 = frr[1], f2 = frr[2], f3 = frr[3];
            A[0]  += f0.x * w; A[1]  += f0.y * w; A[2]  += f0.z * w; A[3]  += f0.w * w;
            A[4]  += f1.x * w; A[5]  += f1.y * w; A[6]  += f1.z * w; A[7]  += f1.w * w;
            A[8]  += f2.x * w; A[9]  += f2.y * w; A[10] += f2.z * w; A[11] += f2.w * w;
            A[12] += f3.x * w; A[13] += f3.y * w; A[14] += f3.z * w; A[15] += f3.w * w;
        }

        // ---- softmax over k (in registers) + weighted pool ----
        float mx = A[0];
        #pragma unroll
        for (int k = 1; k < KNB; ++k) mx = fmaxf(mx, A[k]);
        float e[KNB]; float s = 0.f;
        #pragma unroll
        for (int k = 0; k < KNB; ++k) { e[k] = __expf(A[k] - mx); s += e[k]; }
        const float r = 1.f / s;

        const float4* frd = (const float4*)&feaT[g][d][0];
        const float4 f0 = frd[0], f1 = frd[1], f2 = frd[2], f3 = frd[3];
        float pooled =
              e[0]*f0.x + e[1]*f0.y + e[2]*f0.z + e[3]*f0.w
            + e[4]*f1.x + e[5]*f1.y + e[6]*f1.z + e[7]*f1.w
            + e[8]*f2.x + e[9]*f2.y + e[10]*f2.z + e[11]*f2.w
            + e[12]*f3.x + e[13]*f3.y + e[14]*f3.z + e[15]*f3.w;
        pooledL[g][d] = pooled * r;
        __syncthreads();

        // ---- phase 3: out = lrelu(bn(pooled@W_out) + bn(feat@W_sc)) ----
        float acc_o = 0.f;
        #pragma unroll 8
        for (int c = 0; c < CCAT; ++c)
            acc_o += pooledL[g][c] * W_out[c * COUT + d];
        float acc_s = 0.f;
        #pragma unroll 8
        for (int c = 0; c < CIN; ++c)
            acc_s += featL[g][c] * W_sc[c * COUT + d];

        float y = acc_o * s_o + acc_s * s_s + bias3;
        y = y >= 0.f ? y : 0.2f * y;
        out[(size_t)p * COUT + d] = y;
        __syncthreads();   // protect staging buffers before next iteration
    }
}

extern "C" void kernel_launch(void* const* d_in, const int* in_sizes, int n_in,
                              void* d_out, int out_size, void* d_ws, size_t ws_size,
                              hipStream_t stream)
{
    // input order per setup_inputs(): 0 xyz (unused), 1 feature, 2 raw_neighbors,
    // 3 neighbors_idx, 4..9 nb-MLP params, 10 W_attn, 11..16 out-branch, 17..22 sc-branch
    fp feature = (fp)d_in[1];
    fp raw     = (fp)d_in[2];
    const int* nidx = (const int*)d_in[3];
    fp W_nb = (fp)d_in[4],  b_nb = (fp)d_in[5],  g_nb = (fp)d_in[6];
    fp be_nb = (fp)d_in[7], m_nb = (fp)d_in[8],  v_nb = (fp)d_in[9];
    fp W_attn = (fp)d_in[10];
    fp W_out = (fp)d_in[11], b_out = (fp)d_in[12], g_out = (fp)d_in[13];
    fp be_out = (fp)d_in[14], m_out = (fp)d_in[15], v_out = (fp)d_in[16];
    fp W_sc = (fp)d_in[17], b_sc = (fp)d_in[18], g_sc = (fp)d_in[19];
    fp be_sc = (fp)d_in[20], m_sc = (fp)d_in[21], v_sc = (fp)d_in[22];

    hipLaunchKernelGGL(lfa_kernel, dim3(NBLK), dim3(TPB), 0, stream,
                       feature, raw, nidx,
                       W_nb, b_nb, g_nb, be_nb, m_nb, v_nb,
                       W_attn,
                       W_out, b_out, g_out, be_out, m_out, v_out,
                       W_sc, b_sc, g_sc, be_sc, m_sc, v_sc,
                       (float*)d_out);
}

// Round 3
// 580.932 us; speedup vs baseline: 3.9294x; 3.9294x over previous
//
#include <hip/hip_runtime.h>

// LocalFeatureAggregation — round 2: MFMA rewrite, two kernels.
// K1: per-wave fea build (gather + nb-MLP MFMA) + attn MFMA + softmax/pool -> pooled (fp32, staged in d_out)
// K2: out = lrelu(bn(pooled@W_out) + bn(feat@W_sc)) as M=16 MFMA GEMM, in-place over d_out.

#define KNB   16
#define CR    10
#define CIN   64
#define CCAT  128
#define COUT  128
#define NPTS  131072          // B*N = 2*65536
#define EPS   1e-5f

typedef const float* fp;
typedef short bf16x8 __attribute__((ext_vector_type(8)));
typedef float f32x4  __attribute__((ext_vector_type(4)));

__device__ __forceinline__ unsigned short f2bf(float x) {
    unsigned int u = __float_as_uint(x);
    unsigned int r = (u + 0x7FFFu + ((u >> 16) & 1u)) >> 16;   // RNE
    return (unsigned short)r;
}
__device__ __forceinline__ float bf2f(unsigned short h) {
    return __uint_as_float(((unsigned int)h) << 16);
}
__device__ __forceinline__ float lrelu(float x) { return fmaxf(x, 0.2f * x); }

// ---------------------------------------------------------------------------
// Kernel 1: 512 blocks x 256 thr (4 waves). Each block: 256 points, 32 iters,
// each wave 2 points/iter. No block barriers after one-time staging.
// ---------------------------------------------------------------------------
__global__ __launch_bounds__(256) void lfa_k1(
    fp feature, fp raw, const int* __restrict__ nidx,
    fp W_nb, fp b_nb, fp g_nb, fp be_nb, fp m_nb, fp v_nb,
    fp W_attn,
    float* __restrict__ pooled_out)   // d_out used as pooled[NPTS][128] fp32
{
    // B-fragment layout: [tile][kstep][lane][8 bf16] -> one ds_read_b128/lane
    __shared__ __align__(16) unsigned short WB[8 * 4 * 64 * 8];     // 32768 B
    __shared__ __align__(16) unsigned short feaA[4][2][16][136];    // 34816 B (pitch 136: 16B rows, 2-way banks)
    __shared__ __align__(16) unsigned short WnbB[4 * 64 * 8];       // 4096 B (K padded 10->32 w/ zeros)
    __shared__ float snb[64], binb[64];

    const int tid  = threadIdx.x;
    const int w    = tid >> 6;
    const int lane = tid & 63;
    const int quad = lane >> 4;
    const int l15  = lane & 15;

    // ---- stage W_attn in B-frag order (bf16) ----
    for (int e = tid; e < 2048; e += 256) {            // (n0,s,ln) triples
        const int n0 = e >> 8, s = (e >> 6) & 3, ln = e & 63;
        const int n = (n0 << 4) + (ln & 15);
        #pragma unroll
        for (int j = 0; j < 8; ++j) {
            const int k = (s << 5) + ((ln >> 4) << 3) + j;
            WB[e * 8 + j] = f2bf(W_attn[k * CCAT + n]);
        }
    }
    // ---- stage W_nb in B-frag order, K rows >=10 zeroed ----
    {
        const int n0 = tid >> 6, ln = tid & 63;        // exactly 256 entries
        const int n = (n0 << 4) + (ln & 15);
        #pragma unroll
        for (int j = 0; j < 8; ++j) {
            const int k = ((ln >> 4) << 3) + j;
            WnbB[tid * 8 + j] = (k < CR) ? f2bf(W_nb[k * 64 + n]) : 0;
        }
    }
    if (tid < 64) {
        const float s = g_nb[tid] * rsqrtf(v_nb[tid] + EPS);
        snb[tid]  = s;
        binb[tid] = (b_nb[tid] - m_nb[tid]) * s + be_nb[tid];
    }
    __syncthreads();

    for (int it = 0; it < 32; ++it) {
        #pragma unroll 1
        for (int pt = 0; pt < 2; ++pt) {
            const int p = blockIdx.x * 256 + it * 8 + w * 2 + pt;
            const int b = p >> 16;

            // ---- neighbor indices (lanes 0..15) ----
            int idxv = 0;
            if (lane < 16) idxv = nidx[p * KNB + lane];

            // ---- gather: fea[k][0..63], bf16 into LDS A-layout ----
            #pragma unroll
            for (int i = 0; i < 4; ++i) {
                const int k  = i * 4 + quad;
                const int ni = __shfl(idxv, k, 64);
                const float4 gv = *(const float4*)&feature[(size_t)((b << 16) + ni) * CIN + l15 * 4];
                unsigned int w0 = (unsigned int)f2bf(gv.x) | ((unsigned int)f2bf(gv.y) << 16);
                unsigned int w1 = (unsigned int)f2bf(gv.z) | ((unsigned int)f2bf(gv.w) << 16);
                uint2 pk; pk.x = w0; pk.y = w1;
                *(uint2*)&feaA[w][pt][k][l15 * 4] = pk;
            }

            // ---- nb-MLP: A-frag built directly from raw (K=32, cols>=10 zero) ----
            bf16x8 anb = {0, 0, 0, 0, 0, 0, 0, 0};
            {
                const float* rp = raw + (size_t)p * (KNB * CR) + l15 * CR;
                if (quad == 0) {
                    const float2 r0 = *(const float2*)(rp + 0);
                    const float2 r1 = *(const float2*)(rp + 2);
                    const float2 r2 = *(const float2*)(rp + 4);
                    const float2 r3 = *(const float2*)(rp + 6);
                    anb[0] = (short)f2bf(r0.x); anb[1] = (short)f2bf(r0.y);
                    anb[2] = (short)f2bf(r1.x); anb[3] = (short)f2bf(r1.y);
                    anb[4] = (short)f2bf(r2.x); anb[5] = (short)f2bf(r2.y);
                    anb[6] = (short)f2bf(r3.x); anb[7] = (short)f2bf(r3.y);
                } else if (quad == 1) {
                    const float2 r4 = *(const float2*)(rp + 8);
                    anb[0] = (short)f2bf(r4.x); anb[1] = (short)f2bf(r4.y);
                }
            }
            #pragma unroll
            for (int n0 = 0; n0 < 4; ++n0) {
                const bf16x8 bfr = *(const bf16x8*)&WnbB[(n0 * 64 + lane) * 8];
                f32x4 c = {0.f, 0.f, 0.f, 0.f};
                c = __builtin_amdgcn_mfma_f32_16x16x32_bf16(anb, bfr, c, 0, 0, 0);
                const int d = (n0 << 4) + l15;                 // 0..63
                const float sc = snb[d], bi = binb[d];
                #pragma unroll
                for (int r = 0; r < 4; ++r) {
                    const float x = lrelu(c[r] * sc + bi);
                    feaA[w][pt][quad * 4 + r][64 + d] = f2bf(x);
                }
            }

            // ---- phase 2 A-frags (fea rows, m = l15) ----
            bf16x8 A[4];
            #pragma unroll
            for (int s = 0; s < 4; ++s)
                A[s] = *(const bf16x8*)&feaA[w][pt][l15][s * 32 + quad * 8];

            // ---- per N-tile: 4 MFMA -> softmax over k -> pooled ----
            #pragma unroll 1
            for (int n0 = 0; n0 < 8; ++n0) {
                f32x4 c = {0.f, 0.f, 0.f, 0.f};
                #pragma unroll
                for (int s = 0; s < 4; ++s) {
                    const bf16x8 bfr = *(const bf16x8*)&WB[((n0 * 4 + s) * 64 + lane) * 8];
                    c = __builtin_amdgcn_mfma_f32_16x16x32_bf16(A[s], bfr, c, 0, 0, 0);
                }
                // softmax over k (C rows) for d = n0*16 + l15
                float mx = fmaxf(fmaxf(c[0], c[1]), fmaxf(c[2], c[3]));
                mx = fmaxf(mx, __shfl_xor(mx, 16, 64));
                mx = fmaxf(mx, __shfl_xor(mx, 32, 64));
                float e0 = __expf(c[0] - mx), e1 = __expf(c[1] - mx);
                float e2 = __expf(c[2] - mx), e3 = __expf(c[3] - mx);
                float sm = e0 + e1 + e2 + e3;
                sm += __shfl_xor(sm, 16, 64);
                sm += __shfl_xor(sm, 32, 64);
                const float inv = 1.0f / sm;
                const int d = (n0 << 4) + l15;
                float pp = 0.f;
                #pragma unroll
                for (int r = 0; r < 4; ++r) {
                    const float fv = bf2f(feaA[w][pt][quad * 4 + r][d]);
                    pp += (r == 0 ? e0 : r == 1 ? e1 : r == 2 ? e2 : e3) * fv;
                }
                pp *= inv;
                pp += __shfl_xor(pp, 16, 64);
                pp += __shfl_xor(pp, 32, 64);
                if (lane < 16)
                    pooled_out[(size_t)p * CCAT + d] = pp;
            }
        }
    }
}

// ---------------------------------------------------------------------------
// Kernel 2: 512 blocks x 256 thr (4 waves), each wave 16 points/iter, 4 iters.
// out = lrelu(A[16x192] @ W3hat[192x128] + bias3), A = [pooled | feat], in-place d_out.
// ---------------------------------------------------------------------------
__global__ __launch_bounds__(256) void lfa_k2(
    fp feature,
    fp W_out, fp b_out, fp g_out, fp be_out, fp m_out, fp v_out,
    fp W_sc,  fp b_sc,  fp g_sc,  fp be_sc,  fp m_sc,  fp v_sc,
    float* __restrict__ io)   // d_out: in = pooled rows, out = final rows
{
    __shared__ __align__(16) unsigned short W3[8 * 6 * 64 * 8];   // 49152 B, BN-prescaled
    __shared__ float bias3L[128];

    const int tid  = threadIdx.x;
    const int w    = tid >> 6;
    const int lane = tid & 63;
    const int quad = lane >> 4;
    const int l15  = lane & 15;

    for (int e = tid; e < 3072; e += 256) {
        const int n0 = e / 384, rem = e % 384, s = rem >> 6, ln = rem & 63;
        const int d = (n0 << 4) + (ln & 15);
        #pragma unroll
        for (int j = 0; j < 8; ++j) {
            const int k = (s << 5) + ((ln >> 4) << 3) + j;     // 0..191
            float v;
            if (k < CCAT) v = W_out[k * COUT + d] * (g_out[d] * rsqrtf(v_out[d] + EPS));
            else          v = W_sc[(k - CCAT) * COUT + d] * (g_sc[d] * rsqrtf(v_sc[d] + EPS));
            W3[e * 8 + j] = f2bf(v);
        }
    }
    if (tid < 128) {
        const int d = tid;
        const float so = g_out[d] * rsqrtf(v_out[d] + EPS);
        const float ss = g_sc[d]  * rsqrtf(v_sc[d]  + EPS);
        bias3L[d] = (b_out[d] - m_out[d]) * so + be_out[d]
                  + (b_sc[d]  - m_sc[d])  * ss + be_sc[d];
    }
    __syncthreads();

    #pragma unroll 1
    for (int it = 0; it < 4; ++it) {
        const int p0  = blockIdx.x * 256 + it * 64 + w * 16;
        const int row = p0 + l15;

        // A-frags: k 0..127 = pooled row (from io), 128..191 = feature row
        bf16x8 A[6];
        #pragma unroll
        for (int s = 0; s < 4; ++s) {
            const float4 a0 = *(const float4*)&io[(size_t)row * CCAT + s * 32 + quad * 8];
            const float4 a1 = *(const float4*)&io[(size_t)row * CCAT + s * 32 + quad * 8 + 4];
            A[s][0] = (short)f2bf(a0.x); A[s][1] = (short)f2bf(a0.y);
            A[s][2] = (short)f2bf(a0.z); A[s][3] = (short)f2bf(a0.w);
            A[s][4] = (short)f2bf(a1.x); A[s][5] = (short)f2bf(a1.y);
            A[s][6] = (short)f2bf(a1.z); A[s][7] = (short)f2bf(a1.w);
        }
        #pragma unroll
        for (int s = 4; s < 6; ++s) {
            const float4 a0 = *(const float4*)&feature[(size_t)row * CIN + (s - 4) * 32 + quad * 8];
            const float4 a1 = *(const float4*)&feature[(size_t)row * CIN + (s - 4) * 32 + quad * 8 + 4];
            A[s][0] = (short)f2bf(a0.x); A[s][1] = (short)f2bf(a0.y);
            A[s][2] = (short)f2bf(a0.z); A[s][3] = (short)f2bf(a0.w);
            A[s][4] = (short)f2bf(a1.x); A[s][5] = (short)f2bf(a1.y);
            A[s][6] = (short)f2bf(a1.z); A[s][7] = (short)f2bf(a1.w);
        }

        #pragma unroll 1
        for (int n0 = 0; n0 < 8; ++n0) {
            f32x4 c = {0.f, 0.f, 0.f, 0.f};
            #pragma unroll
            for (int s = 0; s < 6; ++s) {
                const bf16x8 bfr = *(const bf16x8*)&W3[((n0 * 6 + s) * 64 + lane) * 8];
                c = __builtin_amdgcn_mfma_f32_16x16x32_bf16(A[s], bfr, c, 0, 0, 0);
            }
            const int d = (n0 << 4) + l15;
            const float bz = bias3L[d];
            #pragma unroll
            for (int r = 0; r < 4; ++r)
                io[(size_t)(p0 + quad * 4 + r) * COUT + d] = lrelu(c[r] + bz);
        }
    }
}

extern "C" void kernel_launch(void* const* d_in, const int* in_sizes, int n_in,
                              void* d_out, int out_size, void* d_ws, size_t ws_size,
                              hipStream_t stream)
{
    fp feature = (fp)d_in[1];
    fp raw     = (fp)d_in[2];
    const int* nidx = (const int*)d_in[3];
    fp W_nb = (fp)d_in[4],  b_nb = (fp)d_in[5],  g_nb = (fp)d_in[6];
    fp be_nb = (fp)d_in[7], m_nb = (fp)d_in[8],  v_nb = (fp)d_in[9];
    fp W_attn = (fp)d_in[10];
    fp W_out = (fp)d_in[11], b_out = (fp)d_in[12], g_out = (fp)d_in[13];
    fp be_out = (fp)d_in[14], m_out = (fp)d_in[15], v_out = (fp)d_in[16];
    fp W_sc = (fp)d_in[17], b_sc = (fp)d_in[18], g_sc = (fp)d_in[19];
    fp be_sc = (fp)d_in[20], m_sc = (fp)d_in[21], v_sc = (fp)d_in[22];

    hipLaunchKernelGGL(lfa_k1, dim3(512), dim3(256), 0, stream,
                       feature, raw, nidx,
                       W_nb, b_nb, g_nb, be_nb, m_nb, v_nb,
                       W_attn, (float*)d_out);
    hipLaunchKernelGGL(lfa_k2, dim3(512), dim3(256), 0, stream,
                       feature,
                       W_out, b_out, g_out, be_out, m_out, v_out,
                       W_sc, b_sc, g_sc, be_sc, m_sc, v_sc,
                       (float*)d_out);
}

// Round 4
// 429.834 us; speedup vs baseline: 5.3107x; 1.3515x over previous
//
#include <hip/hip_runtime.h>

// LocalFeatureAggregation — round 3: single fused MFMA kernel (barrier-free per-wave),
// W_attn B-frags in registers, BN folded into weights, phase-3 GEMM fused per 16 points.
// Requires ws_size >= 86784 bytes (prep kernel stages frag tables into d_ws).

#define KNB   16
#define CR    10
#define CIN   64
#define CCAT  128
#define COUT  128
#define NPTS  131072
#define EPS   1e-5f

// d_ws layout (bytes)
#define WS_WB   0        // W_attn B-frags: 2048 * 16 B = 32768
#define WS_W3   32768    // [W_out;W_sc] BN-folded B-frags: 3072 * 16 B = 49152
#define WS_WNB  81920    // W_nb BN-folded B-frags (K padded to 32): 256 * 16 B = 4096
#define WS_B3   86016    // bias3[128] fp32
#define WS_BNB  86528    // binb[64] fp32   -> total 86784

typedef const float* fp;
typedef short bf16x8 __attribute__((ext_vector_type(8)));
typedef float f32x4  __attribute__((ext_vector_type(4)));

__device__ __forceinline__ unsigned short f2bf(float x) {
    unsigned int u = __float_as_uint(x);
    return (unsigned short)((u + 0x7FFFu + ((u >> 16) & 1u)) >> 16);   // RNE
}
__device__ __forceinline__ unsigned int pack2(float a, float b) {
    return (unsigned int)f2bf(a) | ((unsigned int)f2bf(b) << 16);
}
__device__ __forceinline__ float bf2f(unsigned short h) {
    return __uint_as_float(((unsigned int)h) << 16);
}
__device__ __forceinline__ float lrelu(float x) { return fmaxf(x, 0.2f * x); }

// ---------------------------------------------------------------------------
// Prep: build all weight-fragment tables in d_ws (runs every launch; d_ws is
// re-poisoned by the harness before each timed call).
// ---------------------------------------------------------------------------
__global__ __launch_bounds__(256) void lfa_prep(
    fp W_nb, fp b_nb, fp g_nb, fp be_nb, fp m_nb, fp v_nb,
    fp W_attn,
    fp W_out, fp b_out, fp g_out, fp be_out, fp m_out, fp v_out,
    fp W_sc,  fp b_sc,  fp g_sc,  fp be_sc,  fp m_sc,  fp v_sc,
    unsigned char* __restrict__ ws)
{
    const int t = blockIdx.x * 256 + threadIdx.x;
    if (t < 2048) {                                   // W_attn frags
        const int n0 = t >> 8, s = (t >> 6) & 3, ln = t & 63;
        const int n = (n0 << 4) + (ln & 15);
        unsigned int v[4];
        #pragma unroll
        for (int jj = 0; jj < 4; ++jj) {
            const int k = (s << 5) + ((ln >> 4) << 3) + jj * 2;
            v[jj] = pack2(W_attn[k * CCAT + n], W_attn[(k + 1) * CCAT + n]);
        }
        *(uint4*)(ws + WS_WB + t * 16) = make_uint4(v[0], v[1], v[2], v[3]);
    } else if (t < 5120) {                            // [W_out;W_sc] BN-folded frags
        const int e = t - 2048;
        const int t8 = e / 384, rem = e % 384, s = rem >> 6, ln = rem & 63;
        const int d = (t8 << 4) + (ln & 15);
        const float so = g_out[d] * rsqrtf(v_out[d] + EPS);
        const float ss = g_sc[d]  * rsqrtf(v_sc[d]  + EPS);
        unsigned int v[4];
        #pragma unroll
        for (int jj = 0; jj < 4; ++jj) {
            float a[2];
            #pragma unroll
            for (int h = 0; h < 2; ++h) {
                const int k = (s << 5) + ((ln >> 4) << 3) + jj * 2 + h;   // 0..191
                a[h] = (k < CCAT) ? W_out[k * COUT + d] * so
                                  : W_sc[(k - CCAT) * COUT + d] * ss;
            }
            v[jj] = pack2(a[0], a[1]);
        }
        *(uint4*)(ws + WS_W3 + e * 16) = make_uint4(v[0], v[1], v[2], v[3]);
    } else if (t < 5376) {                            // W_nb BN-prescaled frags
        const int e = t - 5120;
        const int n0 = e >> 6, ln = e & 63;
        const int n = (n0 << 4) + (ln & 15);
        const float sn = g_nb[n] * rsqrtf(v_nb[n] + EPS);
        unsigned int v[4];
        #pragma unroll
        for (int jj = 0; jj < 4; ++jj) {
            float a[2];
            #pragma unroll
            for (int h = 0; h < 2; ++h) {
                const int k = ((ln >> 4) << 3) + jj * 2 + h;
                a[h] = (k < CR) ? W_nb[k * 64 + n] * sn : 0.f;
            }
            v[jj] = pack2(a[0], a[1]);
        }
        *(uint4*)(ws + WS_WNB + e * 16) = make_uint4(v[0], v[1], v[2], v[3]);
    } else if (t < 5504) {                            // bias3
        const int d = t - 5376;
        const float so = g_out[d] * rsqrtf(v_out[d] + EPS);
        const float ss = g_sc[d]  * rsqrtf(v_sc[d]  + EPS);
        ((float*)(ws + WS_B3))[d] =
              (b_out[d] - m_out[d]) * so + be_out[d]
            + (b_sc[d]  - m_sc[d])  * ss + be_sc[d];
    } else if (t < 5568) {                            // nb bias
        const int d = t - 5504;
        const float sn = g_nb[d] * rsqrtf(v_nb[d] + EPS);
        ((float*)(ws + WS_BNB))[d] = (b_nb[d] - m_nb[d]) * sn + be_nb[d];
    }
}

// ---------------------------------------------------------------------------
// Main: 2048 blocks x 256 thr (4 waves). Each wave owns 16 consecutive points:
// 8 iters x 2 points (gather + nb-MLP MFMA + attn MFMA + softmax/pool into a
// per-wave LDS slab), then one fused M=16,K=192 MFMA GEMM epilogue. No barriers.
// ---------------------------------------------------------------------------
__global__ __launch_bounds__(256, 2) void lfa_main(
    fp feature, fp raw, const int* __restrict__ nidx,
    const unsigned char* __restrict__ ws, float* __restrict__ out)
{
    __shared__ __align__(16) unsigned short feaA[4][2][16][136];    // 34816 B
    __shared__ __align__(16) unsigned short pooledA[4][16][200];    // 25600 B ([pooled|feat] A-layout)

    const int tid  = threadIdx.x;
    const int w    = tid >> 6;
    const int lane = tid & 63;
    const int quad = lane >> 4;
    const int l15  = lane & 15;
    const int p0   = (blockIdx.x * 4 + w) * 16;    // wave's 16 points
    const int b    = p0 >> 16;                     // batch (16-pt range never straddles)

    // ---- invariant B-frags: W_attn in registers (128 VGPRs) ----
    bf16x8 WB[8][4];
    #pragma unroll
    for (int n0 = 0; n0 < 8; ++n0)
        #pragma unroll
        for (int s = 0; s < 4; ++s)
            WB[n0][s] = *(const bf16x8*)(ws + WS_WB + (((n0 * 4 + s) * 64 + lane) << 4));

    float binb[4];
    #pragma unroll
    for (int j = 0; j < 4; ++j)
        binb[j] = ((const float*)(ws + WS_BNB))[j * 16 + l15];

    #pragma unroll 1
    for (int it = 0; it < 8; ++it) {
        const int pp0 = p0 + it * 2;

        // neighbor indices for both points (lanes 0..31; contiguous layout)
        int idxv = 0;
        if (lane < 32) idxv = nidx[pp0 * KNB + lane];

        // stage both center-feature rows into pooledA cols 128..191 (bf16)
        if (lane < 32) {
            const int pt = lane >> 4, c4 = l15 * 4;
            const float4 cf = *(const float4*)&feature[(size_t)(pp0 + pt) * CIN + c4];
            uint2 pk; pk.x = pack2(cf.x, cf.y); pk.y = pack2(cf.z, cf.w);
            *(uint2*)&pooledA[w][it * 2 + pt][CCAT + c4] = pk;
        }

        #pragma unroll
        for (int pt = 0; pt < 2; ++pt) {
            const int p = pp0 + pt;

            // ---- gather loads (issued early, consumed after nb-MLP) ----
            float4 gv[4];
            #pragma unroll
            for (int i = 0; i < 4; ++i) {
                const int ni = __shfl(idxv, pt * 16 + i * 4 + quad, 64);
                gv[i] = *(const float4*)&feature[(size_t)((b << 16) + ni) * CIN + l15 * 4];
            }

            // ---- nb-MLP A-frag directly from raw (K padded 10->32) ----
            bf16x8 anb = {0, 0, 0, 0, 0, 0, 0, 0};
            {
                const float* rp = raw + (size_t)p * (KNB * CR) + l15 * CR;
                if (quad == 0) {
                    const float2 r0 = *(const float2*)(rp + 0);
                    const float2 r1 = *(const float2*)(rp + 2);
                    const float2 r2 = *(const float2*)(rp + 4);
                    const float2 r3 = *(const float2*)(rp + 6);
                    anb[0] = (short)f2bf(r0.x); anb[1] = (short)f2bf(r0.y);
                    anb[2] = (short)f2bf(r1.x); anb[3] = (short)f2bf(r1.y);
                    anb[4] = (short)f2bf(r2.x); anb[5] = (short)f2bf(r2.y);
                    anb[6] = (short)f2bf(r3.x); anb[7] = (short)f2bf(r3.y);
                } else if (quad == 1) {
                    const float2 r4 = *(const float2*)(rp + 8);
                    anb[0] = (short)f2bf(r4.x); anb[1] = (short)f2bf(r4.y);
                }
            }

            // ---- nb-MLP MFMA (W prescaled by BN); keep outputs for pool ----
            float nbC[4][4];
            #pragma unroll
            for (int n0 = 0; n0 < 4; ++n0) {
                const bf16x8 bw = *(const bf16x8*)(ws + WS_WNB + ((n0 * 64 + lane) << 4));
                f32x4 c = {0.f, 0.f, 0.f, 0.f};
                c = __builtin_amdgcn_mfma_f32_16x16x32_bf16(anb, bw, c, 0, 0, 0);
                #pragma unroll
                for (int r = 0; r < 4; ++r) {
                    const float x = lrelu(c[r] + binb[n0]);
                    nbC[n0][r] = x;
                    feaA[w][pt][quad * 4 + r][64 + n0 * 16 + l15] = f2bf(x);
                }
            }

            // ---- gather writes (A-layout rows, b64) ----
            #pragma unroll
            for (int i = 0; i < 4; ++i) {
                uint2 pk; pk.x = pack2(gv[i].x, gv[i].y); pk.y = pack2(gv[i].z, gv[i].w);
                *(uint2*)&feaA[w][pt][i * 4 + quad][l15 * 4] = pk;
            }

            // ---- attn A-frags ----
            bf16x8 A[4];
            #pragma unroll
            for (int s = 0; s < 4; ++s)
                A[s] = *(const bf16x8*)&feaA[w][pt][l15][s * 32 + quad * 8];

            // ---- 8 d-tiles: MFMA -> softmax over k (no max-sub) -> pool ----
            #pragma unroll
            for (int n0 = 0; n0 < 8; ++n0) {
                f32x4 c = {0.f, 0.f, 0.f, 0.f};
                #pragma unroll
                for (int s = 0; s < 4; ++s)
                    c = __builtin_amdgcn_mfma_f32_16x16x32_bf16(A[s], WB[n0][s], c, 0, 0, 0);
                const float e0 = __expf(c[0]), e1 = __expf(c[1]);
                const float e2 = __expf(c[2]), e3 = __expf(c[3]);
                float den = e0 + e1 + e2 + e3;
                float num;
                if (n0 < 4) {
                    num = e0 * bf2f(feaA[w][pt][quad * 4 + 0][n0 * 16 + l15])
                        + e1 * bf2f(feaA[w][pt][quad * 4 + 1][n0 * 16 + l15])
                        + e2 * bf2f(feaA[w][pt][quad * 4 + 2][n0 * 16 + l15])
                        + e3 * bf2f(feaA[w][pt][quad * 4 + 3][n0 * 16 + l15]);
                } else {
                    num = e0 * nbC[n0 - 4][0] + e1 * nbC[n0 - 4][1]
                        + e2 * nbC[n0 - 4][2] + e3 * nbC[n0 - 4][3];
                }
                num += __shfl_xor(num, 16, 64);
                den += __shfl_xor(den, 16, 64);
                num += __shfl_xor(num, 32, 64);
                den += __shfl_xor(den, 32, 64);
                const float pp = __fdividef(num, den);
                if (quad == 0)
                    pooledA[w][it * 2 + pt][n0 * 16 + l15] = f2bf(pp);
            }
        }
    }

    // ---- fused phase 3: out = lrelu([pooled|feat] @ W3hat + bias3), M=16 ----
    bf16x8 A3[6];
    #pragma unroll
    for (int s = 0; s < 6; ++s)
        A3[s] = *(const bf16x8*)&pooledA[w][l15][s * 32 + quad * 8];
    #pragma unroll
    for (int t = 0; t < 8; ++t) {
        f32x4 c = {0.f, 0.f, 0.f, 0.f};
        #pragma unroll
        for (int s = 0; s < 6; ++s) {
            const bf16x8 bw = *(const bf16x8*)(ws + WS_W3 + (((t * 6 + s) * 64 + lane) << 4));
            c = __builtin_amdgcn_mfma_f32_16x16x32_bf16(A3[s], bw, c, 0, 0, 0);
        }
        const float bz = ((const float*)(ws + WS_B3))[t * 16 + l15];
        #pragma unroll
        for (int r = 0; r < 4; ++r)
            out[(size_t)(p0 + quad * 4 + r) * COUT + t * 16 + l15] = lrelu(c[r] + bz);
    }
}

extern "C" void kernel_launch(void* const* d_in, const int* in_sizes, int n_in,
                              void* d_out, int out_size, void* d_ws, size_t ws_size,
                              hipStream_t stream)
{
    fp feature = (fp)d_in[1];
    fp raw     = (fp)d_in[2];
    const int* nidx = (const int*)d_in[3];
    fp W_nb = (fp)d_in[4],  b_nb = (fp)d_in[5],  g_nb = (fp)d_in[6];
    fp be_nb = (fp)d_in[7], m_nb = (fp)d_in[8],  v_nb = (fp)d_in[9];
    fp W_attn = (fp)d_in[10];
    fp W_out = (fp)d_in[11], b_out = (fp)d_in[12], g_out = (fp)d_in[13];
    fp be_out = (fp)d_in[14], m_out = (fp)d_in[15], v_out = (fp)d_in[16];
    fp W_sc = (fp)d_in[17], b_sc = (fp)d_in[18], g_sc = (fp)d_in[19];
    fp be_sc = (fp)d_in[20], m_sc = (fp)d_in[21], v_sc = (fp)d_in[22];

    hipLaunchKernelGGL(lfa_prep, dim3(22), dim3(256), 0, stream,
                       W_nb, b_nb, g_nb, be_nb, m_nb, v_nb,
                       W_attn,
                       W_out, b_out, g_out, be_out, m_out, v_out,
                       W_sc, b_sc, g_sc, be_sc, m_sc, v_sc,
                       (unsigned char*)d_ws);
    hipLaunchKernelGGL(lfa_main, dim3(2048), dim3(256), 0, stream,
                       feature, raw, nidx,
                       (const unsigned char*)d_ws, (float*)d_out);
}